// Round 10
// baseline (106.456 us; speedup 1.0000x reference)
//
#include <hip/hip_runtime.h>

#define BATCH 512
#define SEQ   256
#define CEMB  384
#define HD    64
#define MROWS (BATCH*SEQ)

typedef __bf16 bf16_t;
typedef __bf16 bf16x4 __attribute__((ext_vector_type(4)));
typedef __bf16 bf16x8 __attribute__((ext_vector_type(8)));
typedef float  f32x4  __attribute__((ext_vector_type(4)));
typedef float  f32x16 __attribute__((ext_vector_type(16)));

#define GLOAD_LDS16(gp, lp) \
    __builtin_amdgcn_global_load_lds((const __attribute__((address_space(1))) void*)(gp), \
                                     (__attribute__((address_space(3))) void*)(lp), 16, 0, 0)

// ---------- kernel 1: gather W into 32x32x16-fragment-major bf16 array Wf ----------
// frag g = ks*6 + nc (ks=0..23 K-step of 16, nc=0..5 col-tile of 32)
// element idx = (g*64 + lane)*8 + j ; value = W[k][n] with n = nc*32 + (lane&31),
// k = ks*16 + (lane>>5)*8 + j.  (B-frag layout: col=lane&31, k=(lane>>5)*8+j —
// same family pattern as the verified 16x16 layout.)
__global__ void wconv_kernel(const float* __restrict__ Wq, const float* __restrict__ Wk,
                             const float* __restrict__ Wv, bf16_t* __restrict__ Wf) {
    int idx = blockIdx.x * 256 + threadIdx.x;
    if (idx >= 144 * 512) return;
    int j = idx & 7, lane = (idx >> 3) & 63, g = idx >> 9;
    int nc = g % 6, ks = g / 6;
    int n = nc * 32 + (lane & 31);
    int k = ks * 16 + ((lane >> 5) << 3) + j;
    const float* W = (n < 64) ? Wq : ((n < 128) ? Wk : Wv);
    Wf[idx] = (bf16_t)W[k * HD + (n & 63)];
}

__device__ inline bf16x8 cvt8(float4 a, float4 b) {
    bf16x8 r;
    r[0] = (bf16_t)a.x; r[1] = (bf16_t)a.y; r[2] = (bf16_t)a.z; r[3] = (bf16_t)a.w;
    r[4] = (bf16_t)b.x; r[5] = (bf16_t)b.y; r[6] = (bf16_t)b.z; r[7] = (bf16_t)b.w;
    return r;
}

// ---------- kernel 2: qkv projection — full W in LDS, 32x32x16 MFMA ----------
// 512 blocks x 512 threads (8 waves, 2/SIMD; 144KB LDS -> 1 block/CU resident).
// Each wave owns 32 rows x 192 cols: 24 K-steps x {2 A-float4, 6 ds_read_b128,
// 6 mfma_32x32x16}. Halves ds_read and MFMA-issue counts vs the 16x16 form.
// acc = 6 x f32x16 (96 AGPR); live ~190 regs at 2 waves/SIMD: no spill.
__global__ __launch_bounds__(512, 2)
void qkv_kernel(const float* __restrict__ x, const bf16_t* __restrict__ Wf,
                bf16_t* __restrict__ qg, bf16_t* __restrict__ kg, bf16_t* __restrict__ vg) {
    __shared__ char smem[147456];

    const int tid = threadIdx.x;
    const int w = tid >> 6, lane = tid & 63;
    const int l31 = lane & 31, lh = lane >> 5;

    #pragma unroll
    for (int i = 0; i < 18; ++i)
        GLOAD_LDS16((const char*)Wf + tid * 16 + i * 8192, smem + tid * 16 + i * 8192);
    __syncthreads();

    const char* wp = smem + lane * 16;
    const long rowbase = (long)blockIdx.x * 256 + w * 32;
    const float* aptr = x + (rowbase + l31) * CEMB + lh * 8;

    f32x16 acc[6];
    #pragma unroll
    for (int nc = 0; nc < 6; ++nc)
        #pragma unroll
        for (int r = 0; r < 16; ++r) acc[nc][r] = 0.f;

    #pragma unroll
    for (int p = 0; p < 4; ++p) {
        float4 A[6][2];
        #pragma unroll
        for (int s = 0; s < 6; ++s) {
            A[s][0] = *(const float4*)(aptr + (p * 6 + s) * 16);
            A[s][1] = *(const float4*)(aptr + (p * 6 + s) * 16 + 4);
        }
        #pragma unroll
        for (int s = 0; s < 6; ++s) {
            bf16x8 af = cvt8(A[s][0], A[s][1]);
            const int ks = p * 6 + s;
            #pragma unroll
            for (int nc = 0; nc < 6; ++nc) {
                bf16x8 bf = *(const bf16x8*)(wp + (ks * 6 + nc) * 1024);
                acc[nc] = __builtin_amdgcn_mfma_f32_32x32x16_bf16(af, bf, acc[nc], 0, 0, 0);
            }
        }
    }

    // C/D layout (verified, m74/m101): col = lane&31, row = (reg&3)+8*(reg>>2)+4*(lane>>5)
    #pragma unroll
    for (int nc = 0; nc < 6; ++nc) {
        int col = nc * 32 + l31;
        bf16_t* dst = (col < 64) ? qg : ((col < 128) ? kg : vg);
        int d = col & 63;
        #pragma unroll
        for (int reg = 0; reg < 16; ++reg) {
            long rg = rowbase + (reg & 3) + 8 * (reg >> 2) + 4 * lh;
            dst[rg * HD + d] = (bf16_t)acc[nc][reg];
        }
    }
}

// ---------- kernel 3: causal flash attention, one block per batch (unchanged) ----------
__global__ __launch_bounds__(256, 2)
void attn_kernel(const bf16_t* __restrict__ qg, const bf16_t* __restrict__ kg,
                 const bf16_t* __restrict__ vg, float* __restrict__ out) {
    __shared__ char smem[81920];
    // [0,32768):     K  [256][64] bf16, swizzle ^((s&7)<<4)
    // [32768,65536): Vt [64][256] bf16, swizzle ^((d&7)<<4)
    // [65536,81920): P  per-wave [64][32] bf16, swizzle ^((q&3)<<4)

    const int tid = threadIdx.x;
    const int w = tid >> 6, lane = tid & 63;
    const int l15 = lane & 15, l4 = lane >> 4;
    const long base = (long)blockIdx.x * SEQ * HD;

    for (int it = 0; it < 8; ++it) {
        int i = tid + it * 256;
        int s = i >> 3, cb = (i & 7) * 16;
        bf16x8 kv = *(const bf16x8*)(kg + base + (long)i * 8);
        *(bf16x8*)(smem + s * 128 + (cb ^ ((s & 7) << 4))) = kv;
    }
    for (int it = 0; it < 8; ++it) {
        int i = tid + it * 256;
        int s = i >> 3, d0 = (i & 7) * 8;
        bf16x8 vv = *(const bf16x8*)(vg + base + (long)i * 8);
        #pragma unroll
        for (int j = 0; j < 8; ++j) {
            int d = d0 + j;
            *(bf16_t*)(smem + 32768 + d * 512 + ((s * 2) ^ ((d & 7) << 4))) = vv[j];
        }
    }

    bf16x8 qf[4][2];
    #pragma unroll
    for (int mi = 0; mi < 4; ++mi) {
        int row = mi * 64 + w * 16 + l15;
        #pragma unroll
        for (int kk = 0; kk < 2; ++kk)
            qf[mi][kk] = *(const bf16x8*)(qg + base + (long)row * HD + kk * 32 + l4 * 8);
    }

    __syncthreads();

    f32x4 oacc[4][4];
    float mrow[4][4], lrow[4][4];
    #pragma unroll
    for (int mi = 0; mi < 4; ++mi) {
        #pragma unroll
        for (int di = 0; di < 4; ++di) oacc[mi][di] = f32x4{0.f, 0.f, 0.f, 0.f};
        #pragma unroll
        for (int r = 0; r < 4; ++r) { mrow[mi][r] = -1e30f; lrow[mi][r] = 0.f; }
    }

    char* Pw = smem + 65536 + w * 4096;
    const int ntiles = (w < 2) ? 7 : 8;
    const float LOG2E = 1.44269504089f;

    for (int st = 0; st < ntiles; ++st) {
        f32x4 sacc[4][2];
        #pragma unroll
        for (int mi = 0; mi < 4; ++mi)
            #pragma unroll
            for (int ni = 0; ni < 2; ++ni) sacc[mi][ni] = f32x4{0.f, 0.f, 0.f, 0.f};

        #pragma unroll
        for (int kk = 0; kk < 2; ++kk) {
            #pragma unroll
            for (int ni = 0; ni < 2; ++ni) {
                int s = st * 32 + ni * 16 + l15;
                bf16x8 kf = *(const bf16x8*)(smem + s * 128 + (((kk * 32 + l4 * 8) * 2) ^ ((s & 7) << 4)));
                #pragma unroll
                for (int mi = 0; mi < 4; ++mi) {
                    if (st * 32 <= mi * 64 + w * 16 + 15)
                        sacc[mi][ni] = __builtin_amdgcn_mfma_f32_16x16x32_bf16(qf[mi][kk], kf, sacc[mi][ni], 0, 0, 0);
                }
            }
        }

        #pragma unroll
        for (int mi = 0; mi < 4; ++mi) {
            const int R = mi * 64 + w * 16;
            if (st * 32 > R + 15) continue;
            const bool needmask = (st * 32 + 31 > R);
            #pragma unroll
            for (int r = 0; r < 4; ++r) {
                float s0 = sacc[mi][0][r] * 0.125f;
                float s1 = sacc[mi][1][r] * 0.125f;
                if (needmask) {
                    int row = R + l4 * 4 + r;
                    if (st * 32 + l15 > row)      s0 = -1e30f;
                    if (st * 32 + 16 + l15 > row) s1 = -1e30f;
                }
                float mx = fmaxf(s0, s1);
                mx = fmaxf(mx, __shfl_xor(mx, 1));
                mx = fmaxf(mx, __shfl_xor(mx, 2));
                mx = fmaxf(mx, __shfl_xor(mx, 4));
                mx = fmaxf(mx, __shfl_xor(mx, 8));
                float mold = mrow[mi][r];
                float mnew = fmaxf(mold, mx);
                float alpha = exp2f((mold - mnew) * LOG2E);
                float p0 = exp2f((s0 - mnew) * LOG2E);
                float p1 = exp2f((s1 - mnew) * LOG2E);
                mrow[mi][r] = mnew;
                float rs = p0 + p1;
                rs += __shfl_xor(rs, 1);
                rs += __shfl_xor(rs, 2);
                rs += __shfl_xor(rs, 4);
                rs += __shfl_xor(rs, 8);
                lrow[mi][r] = lrow[mi][r] * alpha + rs;
                #pragma unroll
                for (int di = 0; di < 4; ++di) oacc[mi][di][r] *= alpha;
                int q = mi * 16 + l4 * 4 + r;
                *(bf16_t*)(Pw + q * 64 + ((l15 * 2) ^ ((q & 3) << 4))) = (bf16_t)p0;
                *(bf16_t*)(Pw + q * 64 + ((32 + l15 * 2) ^ ((q & 3) << 4))) = (bf16_t)p1;
            }
        }

        #pragma unroll
        for (int mi = 0; mi < 4; ++mi) {
            if (st * 32 > mi * 64 + w * 16 + 15) continue;
            int q = mi * 16 + l15;
            bf16x8 pf = *(const bf16x8*)(Pw + q * 64 + ((l4 * 16) ^ ((q & 3) << 4)));
            #pragma unroll
            for (int di = 0; di < 4; ++di) {
                int d = di * 16 + l15;
                bf16x8 vf = *(const bf16x8*)(smem + 32768 + d * 512 + (((st * 32 + l4 * 8) * 2) ^ ((d & 7) << 4)));
                oacc[mi][di] = __builtin_amdgcn_mfma_f32_16x16x32_bf16(pf, vf, oacc[mi][di], 0, 0, 0);
            }
        }
    }

    #pragma unroll
    for (int mi = 0; mi < 4; ++mi) {
        #pragma unroll
        for (int r = 0; r < 4; ++r) {
            float inv = 1.f / lrow[mi][r];
            long row = mi * 64 + w * 16 + l4 * 4 + r;
            #pragma unroll
            for (int di = 0; di < 4; ++di)
                out[base + row * HD + di * 16 + l15] = oacc[mi][di][r] * inv;
        }
    }
}

extern "C" void kernel_launch(void* const* d_in, const int* in_sizes, int n_in,
                              void* d_out, int out_size, void* d_ws, size_t ws_size,
                              hipStream_t stream) {
    const float* x  = (const float*)d_in[0];
    const float* Wq = (const float*)d_in[1];
    const float* Wk = (const float*)d_in[2];
    const float* Wv = (const float*)d_in[3];
    float* out = (float*)d_out;

    bf16_t* Wf = (bf16_t*)d_ws;                       // 147,456 B fragment-major W (32x32 frags)
    bf16_t* qg = (bf16_t*)((char*)d_ws + (1 << 20));
    bf16_t* kg = qg + (long)MROWS * HD;
    bf16_t* vg = kg + (long)MROWS * HD;

    wconv_kernel<<<dim3(288), dim3(256), 0, stream>>>(Wq, Wk, Wv, Wf);
    qkv_kernel<<<dim3(512), dim3(512), 0, stream>>>(x, Wf, qg, kg, vg);
    attn_kernel<<<dim3(BATCH), dim3(256), 0, stream>>>(qg, kg, vg, out);
}

// Round 11
// 98.863 us; speedup vs baseline: 1.0768x; 1.0768x over previous
//
#include <hip/hip_runtime.h>

#define BATCH 512
#define SEQ   256
#define CEMB  384
#define HD    64
#define MROWS (BATCH*SEQ)

typedef __bf16 bf16_t;
typedef __bf16 bf16x4 __attribute__((ext_vector_type(4)));
typedef __bf16 bf16x8 __attribute__((ext_vector_type(8)));
typedef float  f32x4  __attribute__((ext_vector_type(4)));

#define GLOAD_LDS16(gp, lp) \
    __builtin_amdgcn_global_load_lds((const __attribute__((address_space(1))) void*)(gp), \
                                     (__attribute__((address_space(3))) void*)(lp), 16, 0, 0)

// ---------- kernel 1: gather W into MFMA-fragment-major bf16 array Wf (16x16x32) ----------
// Wf element idx = (f*64 + lane)*8 + j ; f = s*12 + ni (s=K-step 0..11, ni=N-tile 0..11)
// value = W_m[k][d] with n = ni*16 + (lane&15), k = s*32 + (lane>>4)*8 + j, m = n/64, d = n%64
__global__ void wconv_kernel(const float* __restrict__ Wq, const float* __restrict__ Wk,
                             const float* __restrict__ Wv, bf16_t* __restrict__ Wf) {
    int idx = blockIdx.x * 256 + threadIdx.x;
    if (idx >= 144 * 512) return;
    int j = idx & 7, lane = (idx >> 3) & 63, f = idx >> 9;
    int ni = f % 12, s = f / 12;
    int n = ni * 16 + (lane & 15);
    int k = s * 32 + ((lane >> 4) << 3) + j;
    const float* W = (n < 64) ? Wq : ((n < 128) ? Wk : Wv);
    Wf[idx] = (bf16_t)W[k * HD + (n & 63)];
}

__device__ inline bf16x8 cvt8(float4 a, float4 b) {
    bf16x8 r;
    r[0] = (bf16_t)a.x; r[1] = (bf16_t)a.y; r[2] = (bf16_t)a.z; r[3] = (bf16_t)a.w;
    r[4] = (bf16_t)b.x; r[5] = (bf16_t)b.y; r[6] = (bf16_t)b.z; r[7] = (bf16_t)b.w;
    return r;
}

// ---------- kernel 2: qkv projection — full W in LDS, 12 waves/block (3/SIMD) ----------
// 683 blocks x 768 threads. Stage all 144KB of Wf once, one barrier, then each wave
// independently computes ONE 16-row unit x 192 cols (12 K-steps x {2 A-float4,
// 12 ds_read_b128, 12 mfma_16x16x32}). 3 waves/SIMD (launch_bounds(768,3), ~170-reg
// cap; live ~110 -> no spill) to cover the global-A latency chains that 2/SIMD
// (r9) left exposed. Tail block: loads clamped, stores predicated.
__global__ __launch_bounds__(768, 3)
void qkv_kernel(const float* __restrict__ x, const bf16_t* __restrict__ Wf,
                bf16_t* __restrict__ qg, bf16_t* __restrict__ kg, bf16_t* __restrict__ vg) {
    __shared__ char smem[147456];

    const int tid = threadIdx.x;
    const int w = tid >> 6, lane = tid & 63;
    const int l15 = lane & 15, l4 = lane >> 4;

    #pragma unroll
    for (int i = 0; i < 12; ++i)
        GLOAD_LDS16((const char*)Wf + tid * 16 + i * 12288, smem + tid * 16 + i * 12288);
    __syncthreads();

    const char* wp = smem + lane * 16;
    const long rowbase = (long)blockIdx.x * 192 + w * 16;
    const long arow = rowbase + l15;
    const long arowc = (arow < MROWS) ? arow : (MROWS - 1);      // clamp for tail block
    const float* aptr = x + arowc * CEMB + l4 * 8;

    f32x4 acc[12];
    #pragma unroll
    for (int ni = 0; ni < 12; ++ni) acc[ni] = f32x4{0.f, 0.f, 0.f, 0.f};

    #pragma unroll
    for (int hf = 0; hf < 2; ++hf) {
        float4 A[6][2];
        #pragma unroll
        for (int s = 0; s < 6; ++s) {
            A[s][0] = *(const float4*)(aptr + (hf * 6 + s) * 32);
            A[s][1] = *(const float4*)(aptr + (hf * 6 + s) * 32 + 4);
        }
        #pragma unroll
        for (int s = 0; s < 6; ++s) {
            bf16x8 af = cvt8(A[s][0], A[s][1]);
            const int ks = hf * 6 + s;
            #pragma unroll
            for (int ni = 0; ni < 12; ++ni) {
                bf16x8 bf = *(const bf16x8*)(wp + (ks * 12 + ni) * 1024);
                acc[ni] = __builtin_amdgcn_mfma_f32_16x16x32_bf16(af, bf, acc[ni], 0, 0, 0);
            }
        }
    }

    if (rowbase < MROWS) {
        #pragma unroll
        for (int ni = 0; ni < 12; ++ni) {
            int col = ni * 16 + l15;
            bf16_t* dst = (col < 64) ? qg : ((col < 128) ? kg : vg);
            int d = col & 63;
            #pragma unroll
            for (int r = 0; r < 4; ++r) {
                long rg = rowbase + l4 * 4 + r;
                dst[rg * HD + d] = (bf16_t)acc[ni][r];
            }
        }
    }
}

// ---------- kernel 3: causal flash attention, one block per batch (unchanged) ----------
__global__ __launch_bounds__(256, 2)
void attn_kernel(const bf16_t* __restrict__ qg, const bf16_t* __restrict__ kg,
                 const bf16_t* __restrict__ vg, float* __restrict__ out) {
    __shared__ char smem[81920];
    // [0,32768):     K  [256][64] bf16, swizzle ^((s&7)<<4)
    // [32768,65536): Vt [64][256] bf16, swizzle ^((d&7)<<4)
    // [65536,81920): P  per-wave [64][32] bf16, swizzle ^((q&3)<<4)

    const int tid = threadIdx.x;
    const int w = tid >> 6, lane = tid & 63;
    const int l15 = lane & 15, l4 = lane >> 4;
    const long base = (long)blockIdx.x * SEQ * HD;

    for (int it = 0; it < 8; ++it) {
        int i = tid + it * 256;
        int s = i >> 3, cb = (i & 7) * 16;
        bf16x8 kv = *(const bf16x8*)(kg + base + (long)i * 8);
        *(bf16x8*)(smem + s * 128 + (cb ^ ((s & 7) << 4))) = kv;
    }
    for (int it = 0; it < 8; ++it) {
        int i = tid + it * 256;
        int s = i >> 3, d0 = (i & 7) * 8;
        bf16x8 vv = *(const bf16x8*)(vg + base + (long)i * 8);
        #pragma unroll
        for (int j = 0; j < 8; ++j) {
            int d = d0 + j;
            *(bf16_t*)(smem + 32768 + d * 512 + ((s * 2) ^ ((d & 7) << 4))) = vv[j];
        }
    }

    bf16x8 qf[4][2];
    #pragma unroll
    for (int mi = 0; mi < 4; ++mi) {
        int row = mi * 64 + w * 16 + l15;
        #pragma unroll
        for (int kk = 0; kk < 2; ++kk)
            qf[mi][kk] = *(const bf16x8*)(qg + base + (long)row * HD + kk * 32 + l4 * 8);
    }

    __syncthreads();

    f32x4 oacc[4][4];
    float mrow[4][4], lrow[4][4];
    #pragma unroll
    for (int mi = 0; mi < 4; ++mi) {
        #pragma unroll
        for (int di = 0; di < 4; ++di) oacc[mi][di] = f32x4{0.f, 0.f, 0.f, 0.f};
        #pragma unroll
        for (int r = 0; r < 4; ++r) { mrow[mi][r] = -1e30f; lrow[mi][r] = 0.f; }
    }

    char* Pw = smem + 65536 + w * 4096;
    const int ntiles = (w < 2) ? 7 : 8;
    const float LOG2E = 1.44269504089f;

    for (int st = 0; st < ntiles; ++st) {
        f32x4 sacc[4][2];
        #pragma unroll
        for (int mi = 0; mi < 4; ++mi)
            #pragma unroll
            for (int ni = 0; ni < 2; ++ni) sacc[mi][ni] = f32x4{0.f, 0.f, 0.f, 0.f};

        #pragma unroll
        for (int kk = 0; kk < 2; ++kk) {
            #pragma unroll
            for (int ni = 0; ni < 2; ++ni) {
                int s = st * 32 + ni * 16 + l15;
                bf16x8 kf = *(const bf16x8*)(smem + s * 128 + (((kk * 32 + l4 * 8) * 2) ^ ((s & 7) << 4)));
                #pragma unroll
                for (int mi = 0; mi < 4; ++mi) {
                    if (st * 32 <= mi * 64 + w * 16 + 15)
                        sacc[mi][ni] = __builtin_amdgcn_mfma_f32_16x16x32_bf16(qf[mi][kk], kf, sacc[mi][ni], 0, 0, 0);
                }
            }
        }

        #pragma unroll
        for (int mi = 0; mi < 4; ++mi) {
            const int R = mi * 64 + w * 16;
            if (st * 32 > R + 15) continue;
            const bool needmask = (st * 32 + 31 > R);
            #pragma unroll
            for (int r = 0; r < 4; ++r) {
                float s0 = sacc[mi][0][r] * 0.125f;
                float s1 = sacc[mi][1][r] * 0.125f;
                if (needmask) {
                    int row = R + l4 * 4 + r;
                    if (st * 32 + l15 > row)      s0 = -1e30f;
                    if (st * 32 + 16 + l15 > row) s1 = -1e30f;
                }
                float mx = fmaxf(s0, s1);
                mx = fmaxf(mx, __shfl_xor(mx, 1));
                mx = fmaxf(mx, __shfl_xor(mx, 2));
                mx = fmaxf(mx, __shfl_xor(mx, 4));
                mx = fmaxf(mx, __shfl_xor(mx, 8));
                float mold = mrow[mi][r];
                float mnew = fmaxf(mold, mx);
                float alpha = exp2f((mold - mnew) * LOG2E);
                float p0 = exp2f((s0 - mnew) * LOG2E);
                float p1 = exp2f((s1 - mnew) * LOG2E);
                mrow[mi][r] = mnew;
                float rs = p0 + p1;
                rs += __shfl_xor(rs, 1);
                rs += __shfl_xor(rs, 2);
                rs += __shfl_xor(rs, 4);
                rs += __shfl_xor(rs, 8);
                lrow[mi][r] = lrow[mi][r] * alpha + rs;
                #pragma unroll
                for (int di = 0; di < 4; ++di) oacc[mi][di][r] *= alpha;
                int q = mi * 16 + l4 * 4 + r;
                *(bf16_t*)(Pw + q * 64 + ((l15 * 2) ^ ((q & 3) << 4))) = (bf16_t)p0;
                *(bf16_t*)(Pw + q * 64 + ((32 + l15 * 2) ^ ((q & 3) << 4))) = (bf16_t)p1;
            }
        }

        #pragma unroll
        for (int mi = 0; mi < 4; ++mi) {
            if (st * 32 > mi * 64 + w * 16 + 15) continue;
            int q = mi * 16 + l15;
            bf16x8 pf = *(const bf16x8*)(Pw + q * 64 + ((l4 * 16) ^ ((q & 3) << 4)));
            #pragma unroll
            for (int di = 0; di < 4; ++di) {
                int d = di * 16 + l15;
                bf16x8 vf = *(const bf16x8*)(smem + 32768 + d * 512 + (((st * 32 + l4 * 8) * 2) ^ ((d & 7) << 4)));
                oacc[mi][di] = __builtin_amdgcn_mfma_f32_16x16x32_bf16(pf, vf, oacc[mi][di], 0, 0, 0);
            }
        }
    }

    #pragma unroll
    for (int mi = 0; mi < 4; ++mi) {
        #pragma unroll
        for (int r = 0; r < 4; ++r) {
            float inv = 1.f / lrow[mi][r];
            long row = mi * 64 + w * 16 + l4 * 4 + r;
            #pragma unroll
            for (int di = 0; di < 4; ++di)
                out[base + row * HD + di * 16 + l15] = oacc[mi][di][r] * inv;
        }
    }
}

extern "C" void kernel_launch(void* const* d_in, const int* in_sizes, int n_in,
                              void* d_out, int out_size, void* d_ws, size_t ws_size,
                              hipStream_t stream) {
    const float* x  = (const float*)d_in[0];
    const float* Wq = (const float*)d_in[1];
    const float* Wk = (const float*)d_in[2];
    const float* Wv = (const float*)d_in[3];
    float* out = (float*)d_out;

    bf16_t* Wf = (bf16_t*)d_ws;                       // 147,456 B fragment-major W
    bf16_t* qg = (bf16_t*)((char*)d_ws + (1 << 20));
    bf16_t* kg = qg + (long)MROWS * HD;
    bf16_t* vg = kg + (long)MROWS * HD;

    wconv_kernel<<<dim3(288), dim3(256), 0, stream>>>(Wq, Wk, Wv, Wf);
    qkv_kernel<<<dim3((MROWS + 191) / 192), dim3(768), 0, stream>>>(x, Wf, qg, kg, vg);
    attn_kernel<<<dim3(BATCH), dim3(256), 0, stream>>>(qg, kg, vg, out);
}